// Round 14
// baseline (136.491 us; speedup 1.0000x reference)
//
#include <hip/hip_runtime.h>
#include <hip/hip_bf16.h>
#include <cstdint>

#define FLT 32
#define TOUT 505
#define TT 2048
#define MROWS 16384
#define QROWS 4040                 // 8*505
#define KDIM 512
#define BK 64
#define NT 8                       // KDIM/BK

typedef float f32x4 __attribute__((ext_vector_type(4)));
typedef __bf16 bf16x8 __attribute__((ext_vector_type(8)));

static __device__ __forceinline__ ushort f2bf(float f) {
  uint32_t u = __float_as_uint(f);
  uint32_t r = (u + 0x7fffu + ((u >> 16) & 1u)) >> 16;
  return (ushort)r;
}
static __device__ __forceinline__ float bf2f(ushort h) {
  return __uint_as_float(((uint32_t)h) << 16);
}
// native casts -> compiler emits v_cvt_pk_bf16_f32 (RNE, same as f2bf)
static __device__ __forceinline__ bf16x8 cvt8(const float4& lo, const float4& hi) {
  bf16x8 v;
  v[0] = (__bf16)lo.x; v[1] = (__bf16)lo.y; v[2] = (__bf16)lo.z; v[3] = (__bf16)lo.w;
  v[4] = (__bf16)hi.x; v[5] = (__bf16)hi.y; v[6] = (__bf16)hi.z; v[7] = (__bf16)hi.w;
  return v;
}

// ---- wprep: W transposes (192 blocks) + bias gather (1 block) --------------
__global__ void wprep_kernel(const float* __restrict__ Wq, const float* __restrict__ Wk,
                             const float* __restrict__ Wv, const float* __restrict__ bq,
                             const float* __restrict__ bk, const float* __restrict__ bv,
                             ushort* __restrict__ wt, float* __restrict__ bias) {
  const int bid = blockIdx.x;
  const int tid = threadIdx.x;
  if (bid < 192) {                        // 64x64 transpose tiles, 3 matrices
    __shared__ ushort lds[64][66];        // 132B stride: conflict-free
    int mat = bid >> 6;                   // 0 Wq, 1 Wk, 2 Wv
    int w = bid & 63;
    int k0 = (w >> 3) * 64, n0 = (w & 7) * 64;
    const float* W = (mat == 0) ? Wq : (mat == 1) ? Wk : Wv;
    int nn = tid & 63;
    #pragma unroll
    for (int r = 0; r < 16; ++r) {
      int kk = r * 4 + (tid >> 6);
      lds[kk][nn] = f2bf(W[(size_t)(k0 + kk) * 512 + n0 + nn]);   // coalesced
    }
    __syncthreads();
    int kk2 = tid & 63;
    #pragma unroll
    for (int r = 0; r < 16; ++r) {
      int nn2 = r * 4 + (tid >> 6);
      wt[(size_t)(mat * 512 + n0 + nn2) * 512 + k0 + kk2] = lds[kk2][nn2];  // coalesced
    }
  } else {
    #pragma unroll
    for (int e = 0; e < 6; ++e) {
      int n = tid * 6 + e;
      const float* bsrc = (n < 512) ? bq : (n < 1024) ? bk : bv;
      bias[n] = bsrc[n & 511];
    }
  }
}

// ---- GEMM: A DIRECT from global fp32 (no As LDS); B staged in 16KB LDS -----
// blocks 0..1023:    kv[16384][1024] = x @ [Wk|Wv]^T + b
// blocks 1024..1151: qc[4040][512]   = gather(x) @ Wq^T + bq
__global__ __launch_bounds__(256, 4) void gemm_kernel(
    const float* __restrict__ xf, const ushort* __restrict__ wt,
    const float* __restrict__ bias, ushort* __restrict__ kv, ushort* __restrict__ qc) {
  __shared__ ushort Bs[128 * 64];         // 16 KB (B only)

  const int tid = threadIdx.x;
  const int lane = tid & 63;
  const int wv = tid >> 6;
  const int bid = blockIdx.x;

  int m0, n0, ost, gather;
  const ushort* wtb;
  const float* biasb;
  ushort* outp;
  if (bid < 1024) {                       // kv partition, XCD swizzle within
    int swz = (bid & 7) * 128 + (bid >> 3);
    m0 = (swz >> 3) * 128; n0 = (swz & 7) * 128;
    wtb = wt + (size_t)512 * KDIM; biasb = bias + 512;
    outp = kv; ost = 1024; gather = 0;
  } else {                                // q partition (tail)
    int b2 = bid - 1024;
    int swz = (b2 & 7) * 16 + (b2 >> 3);
    m0 = (swz >> 2) * 128; n0 = (swz & 3) * 128;
    wtb = wt; biasb = bias;
    outp = qc; ost = 512; gather = 1;
  }

  // B staging sources (R10-verbatim: linear LDS dest, inverse-swizzled col)
  const ushort* bS[4];
  #pragma unroll
  for (int i = 0; i < 4; ++i) {
    int idx = i * 4096 + tid * 16;
    int row = idx >> 7;
    int colb = idx & 127;
    int scol = (colb ^ ((row & 7) << 4)) >> 1;
    bS[i] = wtb + (size_t)(n0 + row) * KDIM + scol;
  }

  const int fr = lane & 15;
  const int fq = lane >> 4;
  const int wr = wv >> 1;
  const int wc = wv & 1;

  // A direct row pointers: MFMA A-frag = 8 consecutive k of one row
  const float* aP[4];
  #pragma unroll
  for (int i = 0; i < 4; ++i) {
    int r = m0 + wr * 64 + i * 16 + fr;
    size_t arow;
    if (gather) {
      if (r > QROWS - 1) r = QROWS - 1;
      int bb = r / TOUT;
      int t2 = r - bb * TOUT;
      arow = (size_t)bb * TT + (size_t)t2 * 4 + FLT / 2;
    } else {
      arow = (size_t)r;
    }
    aP[i] = xf + arow * KDIM;
  }

  f32x4 acc[4][4];
  #pragma unroll
  for (int i = 0; i < 4; ++i)
    #pragma unroll
    for (int j = 0; j < 4; ++j) acc[i][j] = (f32x4){0.f, 0.f, 0.f, 0.f};

  for (int t = 0; t < NT; ++t) {
    __syncthreads();
    const int koff = t * BK;
    #pragma unroll
    for (int i = 0; i < 4; ++i) {
      __builtin_amdgcn_global_load_lds(
          (const __attribute__((address_space(1))) unsigned int*)(bS[i] + koff),
          (__attribute__((address_space(3))) unsigned int*)((char*)Bs + i * 4096 + tid * 16),
          16, 0, 0);
    }
    __syncthreads();                      // waits only B's 4 loads

    #pragma unroll
    for (int ks = 0; ks < 2; ++ks) {
      // A fragments: direct global fp32 -> bf16 in regs (no LDS, no barrier)
      bf16x8 af[4];
      #pragma unroll
      for (int i = 0; i < 4; ++i) {
        const float* p = aP[i] + koff + ks * 32 + fq * 8;
        float4 lo = *reinterpret_cast<const float4*>(p);
        float4 hi = *reinterpret_cast<const float4*>(p + 4);
        af[i] = cvt8(lo, hi);
      }
      bf16x8 bg[4];
      #pragma unroll
      for (int j = 0; j < 4; ++j) {
        int rb = wc * 64 + j * 16 + fr;
        int ca = ks * 64 + fq * 16;
        bg[j] = *reinterpret_cast<const bf16x8*>(
            (const char*)Bs + rb * 128 + (ca ^ ((rb & 7) << 4)));
      }
      #pragma unroll
      for (int i = 0; i < 4; ++i)
        #pragma unroll
        for (int j = 0; j < 4; ++j)
          acc[i][j] = __builtin_amdgcn_mfma_f32_16x16x32_bf16(af[i], bg[j], acc[i][j], 0, 0, 0);
    }
  }

  // epilogue: direct stores (R4/R7-proven).  D: row=(lane>>4)*4+r, col=lane&15
  #pragma unroll
  for (int j = 0; j < 4; ++j) {
    int col = n0 + wc * 64 + j * 16 + fr;
    float bvl = biasb[col];
    #pragma unroll
    for (int i = 0; i < 4; ++i) {
      int rowb = m0 + wr * 64 + i * 16 + fq * 4;
      #pragma unroll
      for (int r = 0; r < 4; ++r) {
        if (!gather || (rowb + r) < QROWS)
          outp[(size_t)(rowb + r) * ost + col] = f2bf(acc[i][j][r] + bvl);
      }
    }
  }
}

// ---------------- windowed attention (R2/R7-proven) ----------------
__global__ __launch_bounds__(256) void attn_kernel(
    const ushort* __restrict__ kv,   // [MROWS][1024] bf16: [k|v]
    const ushort* __restrict__ qc,   // [QROWS][512] bf16 (center q rows)
    float* __restrict__ out) {
  __shared__ float q_lds[KDIM];
  __shared__ float s_lds[FLT];
  __shared__ float p_lds[FLT];

  const int bid = blockIdx.x;
  const int b = bid & 7;                  // batch pinned to XCD (matches gemm)
  const int t = bid >> 3;
  const size_t base_row = (size_t)b * TT + (size_t)t * 4;
  const int tid = threadIdx.x;
  const int lane = tid & 63;
  const int wv = tid >> 6;

  {
    const ushort* qrow = qc + ((size_t)b * TOUT + t) * KDIM;
    uint v = *reinterpret_cast<const uint*>(qrow + tid * 2);
    q_lds[tid * 2]     = bf2f((ushort)(v & 0xffffu));
    q_lds[tid * 2 + 1] = bf2f((ushort)(v >> 16));
  }
  __syncthreads();

  // scores: 8 lanes per filter tap
  const int fl = lane >> 3;
  const int f = wv * 8 + fl;
  const int sub = lane & 7;
  const ushort* krow = kv + (base_row + f) * 1024;
  float acc = 0.f;
  #pragma unroll
  for (int j = 0; j < 8; ++j) {
    int d = (j * 8 + sub) * 8;
    uint4 kv4 = *reinterpret_cast<const uint4*>(krow + d);
    const ushort* ks = reinterpret_cast<const ushort*>(&kv4);
    #pragma unroll
    for (int e = 0; e < 8; ++e) acc += q_lds[d + e] * bf2f(ks[e]);
  }
  acc += __shfl_xor(acc, 1);
  acc += __shfl_xor(acc, 2);
  acc += __shfl_xor(acc, 4);
  if (sub == 0) s_lds[f] = acc * 0.04419417382415922f;  // 1/sqrt(512)
  __syncthreads();

  float m = -1e30f;
  #pragma unroll
  for (int i = 0; i < FLT; ++i) m = fmaxf(m, s_lds[i]);
  if (tid < FLT) p_lds[tid] = __expf(s_lds[tid] - m);
  __syncthreads();
  float sum = 0.f;
  #pragma unroll
  for (int i = 0; i < FLT; ++i) sum += p_lds[i];
  const float inv = 1.f / sum;

  const int d = tid * 2;
  float o0 = 0.f, o1 = 0.f;
  const ushort* vbase = kv + base_row * 1024 + 512 + d;
  #pragma unroll
  for (int ff = 0; ff < FLT; ++ff) {
    uint vvv = *reinterpret_cast<const uint*>(vbase + (size_t)ff * 1024);
    float w = p_lds[ff] * inv;
    o0 += w * bf2f((ushort)(vvv & 0xffffu));
    o1 += w * bf2f((ushort)(vvv >> 16));
  }
  float2* op = reinterpret_cast<float2*>(out + ((size_t)b * TOUT + t) * 512 + d);
  *op = make_float2(o0, o1);
}

// ---------------- launch ----------------
extern "C" void kernel_launch(void* const* d_in, const int* in_sizes, int n_in,
                              void* d_out, int out_size, void* d_ws, size_t ws_size,
                              hipStream_t stream) {
  const float* x  = (const float*)d_in[0];
  const float* Wq = (const float*)d_in[1];
  const float* bq = (const float*)d_in[2];
  const float* Wk = (const float*)d_in[3];
  const float* bk = (const float*)d_in[4];
  const float* Wv = (const float*)d_in[5];
  const float* bv = (const float*)d_in[6];
  float* out = (float*)d_out;

  char* ws = (char*)d_ws;
  ushort* wt   = (ushort*)ws;                        // 1.5 MiB
  float*  bias = (float*)(ws + 1572864);             // 8 KiB
  ushort* kvb  = (ushort*)(ws + 1581056);            // 32 MiB
  ushort* qc   = (ushort*)(ws + 1581056 + 33554432); // 4 MiB

  hipLaunchKernelGGL(wprep_kernel, dim3(193), dim3(256), 0, stream,
                     Wq, Wk, Wv, bq, bk, bv, wt, bias);
  hipLaunchKernelGGL(gemm_kernel, dim3(1152), dim3(256), 0, stream,
                     x, wt, bias, kvb, qc);
  hipLaunchKernelGGL(attn_kernel, dim3(QROWS), dim3(256), 0, stream, kvb, qc, out);
}

// Round 15
// 74.348 us; speedup vs baseline: 1.8358x; 1.8358x over previous
//
#include <hip/hip_runtime.h>
#include <hip/hip_bf16.h>
#include <cstdint>

#define FLT 32
#define TOUT 505
#define TT 2048
#define MROWS 16384
#define QROWS 4040                 // 8*505
#define KDIM 512
#define BK 64
#define NT 8                       // KDIM/BK

typedef float f32x4 __attribute__((ext_vector_type(4)));
typedef __bf16 bf16x8 __attribute__((ext_vector_type(8)));

static __device__ __forceinline__ ushort f2bf(float f) {
  uint32_t u = __float_as_uint(f);
  uint32_t r = (u + 0x7fffu + ((u >> 16) & 1u)) >> 16;
  return (ushort)r;
}
static __device__ __forceinline__ float bf2f(ushort h) {
  return __uint_as_float(((uint32_t)h) << 16);
}
static __device__ __forceinline__ void pack8(const float4& lo, const float4& hi, ushort* v8) {
  v8[0] = f2bf(lo.x); v8[1] = f2bf(lo.y); v8[2] = f2bf(lo.z); v8[3] = f2bf(lo.w);
  v8[4] = f2bf(hi.x); v8[5] = f2bf(hi.y); v8[6] = f2bf(hi.z); v8[7] = f2bf(hi.w);
}

// ---- wprep: 3 W transposes only (bk dropped exactly; bq,bv used raw) -------
__global__ void wprep_kernel(const float* __restrict__ Wq, const float* __restrict__ Wk,
                             const float* __restrict__ Wv, ushort* __restrict__ wt) {
  const int bid = blockIdx.x;
  const int tid = threadIdx.x;
  __shared__ ushort lds[64][66];          // 132B stride: conflict-free
  int mat = bid >> 6;                     // 0 Wq, 1 Wk, 2 Wv
  int w = bid & 63;
  int k0 = (w >> 3) * 64, n0 = (w & 7) * 64;
  const float* W = (mat == 0) ? Wq : (mat == 1) ? Wk : Wv;
  int nn = tid & 63;
  #pragma unroll
  for (int r = 0; r < 16; ++r) {
    int kk = r * 4 + (tid >> 6);
    lds[kk][nn] = f2bf(W[(size_t)(k0 + kk) * 512 + n0 + nn]);     // coalesced
  }
  __syncthreads();
  int kk2 = tid & 63;
  #pragma unroll
  for (int r = 0; r < 16; ++r) {
    int nn2 = r * 4 + (tid >> 6);
    wt[(size_t)(mat * 512 + n0 + nn2) * 512 + k0 + kk2] = lds[kk2][nn2];  // coalesced
  }
}

// ---- qk GEMM (R10 body): 512 k-blocks + 128 gathered-q blocks --------------
// blocks 0..511:   kb[16384][512] = x @ Wk^T          (no bias: exact)
// blocks 512..639: qc[4040][512]  = gather(x) @ Wq^T + bq
__global__ __launch_bounds__(256, 2) void gemm_kernel(
    const float* __restrict__ xf, const ushort* __restrict__ wt,
    const float* __restrict__ bq, ushort* __restrict__ kb, ushort* __restrict__ qc) {
  __shared__ char smem[33792];            // As 16K | Bs 16K ; epilogue [128][132]
  ushort* const As = (ushort*)smem;
  ushort* const Bs = (ushort*)(smem + 16384);

  const int tid = threadIdx.x;
  const int lane = tid & 63;
  const int wv = tid >> 6;
  const int bid = blockIdx.x;

  int m0, n0, gather, mlim;
  const ushort* wtb;
  ushort* outp;
  if (bid < 512) {                        // k partition, XCD swizzle within
    int swz = (bid & 7) * 64 + (bid >> 3);
    m0 = (swz >> 2) * 128; n0 = (swz & 3) * 128;
    wtb = wt + (size_t)512 * KDIM;        // Wk^T
    outp = kb; gather = 0; mlim = MROWS;
  } else {                                // q partition (tail)
    int b2 = bid - 512;
    int swz = (b2 & 7) * 16 + (b2 >> 3);
    m0 = (swz >> 2) * 128; n0 = (swz & 3) * 128;
    wtb = wt;                             // Wq^T
    outp = qc; gather = 1; mlim = QROWS;
  }

  // staging: A fp32 reg-stage->bf16 swizzled ds_write; B global_load_lds
  const float* aF[4];
  uint aDst[4];
  const ushort* bS[4];
  #pragma unroll
  for (int i = 0; i < 4; ++i) {
    int idx = i * 4096 + tid * 16;        // linear byte off in 16 KB tile
    int row = idx >> 7;                   // 128 B per tile row
    int colb = idx & 127;
    aDst[i] = (uint)(row * 128 + (colb ^ ((row & 7) << 4)));
    int scol = (colb ^ ((row & 7) << 4)) >> 1;
    size_t arow;
    if (gather) {
      int r = m0 + row;
      if (r > QROWS - 1) r = QROWS - 1;
      int bb = r / TOUT;
      int t2 = r - bb * TOUT;
      arow = (size_t)bb * TT + (size_t)t2 * 4 + FLT / 2;
    } else {
      arow = (size_t)(m0 + row);
    }
    aF[i] = xf + arow * KDIM + (colb >> 1);
    bS[i] = wtb + (size_t)(n0 + row) * KDIM + scol;
  }

  const int fr = lane & 15;
  const int fq = lane >> 4;
  const int wr = wv >> 1;
  const int wc = wv & 1;

  f32x4 acc[4][4];
  #pragma unroll
  for (int i = 0; i < 4; ++i)
    #pragma unroll
    for (int j = 0; j < 4; ++j) acc[i][j] = (f32x4){0.f, 0.f, 0.f, 0.f};

  for (int t = 0; t < NT; ++t) {
    __syncthreads();
    const int koff = t * BK;
    #pragma unroll
    for (int i = 0; i < 4; ++i) {
      __builtin_amdgcn_global_load_lds(
          (const __attribute__((address_space(1))) unsigned int*)(bS[i] + koff),
          (__attribute__((address_space(3))) unsigned int*)((char*)Bs + i * 4096 + tid * 16),
          16, 0, 0);
    }
    #pragma unroll
    for (int i = 0; i < 4; ++i) {
      float4 lo = *reinterpret_cast<const float4*>(aF[i] + koff);
      float4 hi = *reinterpret_cast<const float4*>(aF[i] + koff + 4);
      ushort v8[8]; pack8(lo, hi, v8);
      *reinterpret_cast<uint4*>((char*)As + aDst[i]) = *reinterpret_cast<const uint4*>(v8);
    }
    __syncthreads();

    #pragma unroll
    for (int ks = 0; ks < 2; ++ks) {
      bf16x8 af[4], bg[4];
      #pragma unroll
      for (int i = 0; i < 4; ++i) {
        int ra = wr * 64 + i * 16 + fr;
        int ca = ks * 64 + fq * 16;
        af[i] = *reinterpret_cast<const bf16x8*>(
            (const char*)As + ra * 128 + (ca ^ ((ra & 7) << 4)));
        int rb = wc * 64 + i * 16 + fr;
        bg[i] = *reinterpret_cast<const bf16x8*>(
            (const char*)Bs + rb * 128 + (ca ^ ((rb & 7) << 4)));
      }
      #pragma unroll
      for (int i = 0; i < 4; ++i)
        #pragma unroll
        for (int j = 0; j < 4; ++j)
          acc[i][j] = __builtin_amdgcn_mfma_f32_16x16x32_bf16(af[i], bg[j], acc[i][j], 0, 0, 0);
    }
  }

  // epilogue: (bias for q only) -> LDS bf16 [128][132] -> coalesced 16B stores
  __syncthreads();
  ushort* const ep = (ushort*)smem;
  #pragma unroll
  for (int j = 0; j < 4; ++j) {
    int col = n0 + wc * 64 + j * 16 + fr;        // 0..511
    int coll = wc * 64 + j * 16 + fr;
    float bvl = gather ? bq[col] : 0.f;
    #pragma unroll
    for (int i = 0; i < 4; ++i) {
      int rowl = wr * 64 + i * 16 + fq * 4;
      #pragma unroll
      for (int r = 0; r < 4; ++r)
        ep[(rowl + r) * 132 + coll] = f2bf(acc[i][j][r] + bvl);
    }
  }
  __syncthreads();
  #pragma unroll
  for (int it = 0; it < 8; ++it) {
    int row = it * 16 + (tid >> 4);
    int gr = m0 + row;
    if (gr < mlim) {
      uint4 val = *reinterpret_cast<const uint4*>(&ep[row * 132 + (tid & 15) * 8]);
      *reinterpret_cast<uint4*>(outp + (size_t)gr * 512 + n0 + (tid & 15) * 8) = val;
    }
  }
}

// ---- attn: scores = q.k (direct k reads); u = sum w_f x_f (swizzled xw) ----
// 512 blocks: 8 batches x 64 groups of 8 t's sharing one staged x-window
__global__ __launch_bounds__(256) void attn_kernel(
    const float* __restrict__ xf,     // [8*2048][512] fp32
    const ushort* __restrict__ kb,    // [16384][512] bf16
    const ushort* __restrict__ qc,    // [4040][512] bf16
    ushort* __restrict__ ubuf) {      // [4040][512] bf16
  __shared__ char xw[61440];          // [60][1024B] bf16 XOR-swizzled
  __shared__ float q_lds[512];
  __shared__ float s_lds[FLT];
  __shared__ float p_lds[FLT];

  const int bid = blockIdx.x;
  const int b = bid & 7;              // batch pinned to XCD (matches gemm)
  const int g = bid >> 3;             // 0..63
  const int t0 = g * 8;
  const int nt = min(8, TOUT - t0);   // 8, or 1 for g=63
  const int rows = 4 * (nt - 1) + 32; // 60 or 32
  const size_t base_row = (size_t)b * TT + (size_t)t0 * 4;
  const int tid = threadIdx.x;
  const int lane = tid & 63;
  const int wv = tid >> 6;

  // stage x window fp32 -> bf16, XOR-swizzled rows (R9-verified pattern)
  #pragma unroll
  for (int i = 0; i < 15; ++i) {
    int gi = i * 2048 + tid * 8;
    int row = gi >> 9;
    int col = gi & 511;
    if (row < rows) {
      const float* src = xf + (base_row + row) * 512 + col;
      float4 lo = *reinterpret_cast<const float4*>(src);
      float4 hi = *reinterpret_cast<const float4*>(src + 4);
      ushort v8[8]; pack8(lo, hi, v8);
      *reinterpret_cast<uint4*>(xw + row * 1024 + ((2 * col) ^ ((row & 7) << 4))) =
          *reinterpret_cast<const uint4*>(v8);
    }
  }

  for (int tt = 0; tt < nt; ++tt) {
    {  // q row -> LDS fp32
      uint v = *reinterpret_cast<const uint*>(
          qc + ((size_t)b * TOUT + t0 + tt) * 512 + tid * 2);
      q_lds[tid * 2]     = bf2f((ushort)(v & 0xffffu));
      q_lds[tid * 2 + 1] = bf2f((ushort)(v >> 16));
    }
    __syncthreads();                  // xw (first iter) + q ready

    // scores: 8 lanes per filter tap, k read direct from global (L2-hot)
    const int f = wv * 8 + (lane >> 3);
    const int sub = lane & 7;
    const ushort* krow = kb + (base_row + (size_t)(4 * tt + f)) * 512;
    float acc = 0.f;
    #pragma unroll
    for (int j = 0; j < 8; ++j) {
      int d = (j * 8 + sub) * 8;
      uint4 kv4 = *reinterpret_cast<const uint4*>(krow + d);
      const ushort* ks = reinterpret_cast<const ushort*>(&kv4);
      #pragma unroll
      for (int e = 0; e < 8; ++e) acc += q_lds[d + e] * bf2f(ks[e]);
    }
    acc += __shfl_xor(acc, 1);
    acc += __shfl_xor(acc, 2);
    acc += __shfl_xor(acc, 4);
    if (sub == 0) s_lds[f] = acc * 0.04419417382415922f;   // 1/sqrt(512)
    __syncthreads();

    float m = -1e30f;
    #pragma unroll
    for (int i2 = 0; i2 < FLT; ++i2) m = fmaxf(m, s_lds[i2]);
    if (tid < FLT) p_lds[tid] = __expf(s_lds[tid] - m);
    __syncthreads();
    float sum = 0.f;
    #pragma unroll
    for (int i2 = 0; i2 < FLT; ++i2) sum += p_lds[i2];
    const float inv = 1.f / sum;

    // u = sum_f w_f x_f  (2 dims/thread, swizzled LDS reads)
    const int d = tid * 2;
    float o0 = 0.f, o1 = 0.f;
    #pragma unroll
    for (int ff = 0; ff < FLT; ++ff) {
      int r2 = 4 * tt + ff;
      uint vv = *reinterpret_cast<const uint*>(
          xw + r2 * 1024 + ((2 * d) ^ ((r2 & 7) << 4)));
      float w = p_lds[ff] * inv;
      o0 += w * bf2f((ushort)(vv & 0xffffu));
      o1 += w * bf2f((ushort)(vv >> 16));
    }
    uint pk = ((uint)f2bf(o1) << 16) | (uint)f2bf(o0);
    *reinterpret_cast<uint*>(ubuf + ((size_t)b * TOUT + t0 + tt) * 512 + d) = pk;
    __syncthreads();                  // protect q/s/p for next tt
  }
}

// ---- ogemm (R7-proven body): out = u @ Wv^T + bv, fp32 stores --------------
__global__ __launch_bounds__(256, 2) void ogemm_kernel(
    const ushort* __restrict__ ubuf, const ushort* __restrict__ wvt,
    const float* __restrict__ bv, float* __restrict__ out) {
  __shared__ ushort As[128 * 64];
  __shared__ ushort Bs[128 * 64];

  const int tid = threadIdx.x;
  const int lane = tid & 63;
  const int wv = tid >> 6;
  const int swz = (blockIdx.x & 7) * 16 + (blockIdx.x >> 3);
  const int m0 = (swz >> 2) * 128;
  const int n0 = (swz & 3) * 128;

  const ushort* aS[4];
  const ushort* bS[4];
  #pragma unroll
  for (int i = 0; i < 4; ++i) {
    int idx = i * 4096 + tid * 16;
    int row = idx >> 7;
    int colb = idx & 127;
    int scol = (colb ^ ((row & 7) << 4)) >> 1;
    int r = m0 + row; if (r > QROWS - 1) r = QROWS - 1;
    aS[i] = ubuf + (size_t)r * KDIM + scol;
    bS[i] = wvt + (size_t)(n0 + row) * KDIM + scol;
  }

  const int fr = lane & 15;
  const int fq = lane >> 4;
  const int wr = wv >> 1;
  const int wc = wv & 1;

  f32x4 acc[4][4];
  #pragma unroll
  for (int i = 0; i < 4; ++i)
    #pragma unroll
    for (int j = 0; j < 4; ++j) acc[i][j] = (f32x4){0.f, 0.f, 0.f, 0.f};

  for (int t = 0; t < NT; ++t) {
    __syncthreads();
    const int koff = t * BK;
    #pragma unroll
    for (int i = 0; i < 4; ++i) {
      int ldst = i * 4096 + tid * 16;
      __builtin_amdgcn_global_load_lds(
          (const __attribute__((address_space(1))) unsigned int*)(aS[i] + koff),
          (__attribute__((address_space(3))) unsigned int*)((char*)As + ldst),
          16, 0, 0);
      __builtin_amdgcn_global_load_lds(
          (const __attribute__((address_space(1))) unsigned int*)(bS[i] + koff),
          (__attribute__((address_space(3))) unsigned int*)((char*)Bs + ldst),
          16, 0, 0);
    }
    __syncthreads();

    #pragma unroll
    for (int ks = 0; ks < 2; ++ks) {
      bf16x8 af[4], bg[4];
      #pragma unroll
      for (int i = 0; i < 4; ++i) {
        int ra = wr * 64 + i * 16 + fr;
        int ca = ks * 64 + fq * 16;
        af[i] = *reinterpret_cast<const bf16x8*>(
            (const char*)As + ra * 128 + (ca ^ ((ra & 7) << 4)));
        int rb = wc * 64 + i * 16 + fr;
        bg[i] = *reinterpret_cast<const bf16x8*>(
            (const char*)Bs + rb * 128 + (ca ^ ((rb & 7) << 4)));
      }
      #pragma unroll
      for (int i = 0; i < 4; ++i)
        #pragma unroll
        for (int j = 0; j < 4; ++j)
          acc[i][j] = __builtin_amdgcn_mfma_f32_16x16x32_bf16(af[i], bg[j], acc[i][j], 0, 0, 0);
    }
  }

  #pragma unroll
  for (int j = 0; j < 4; ++j) {
    int col = n0 + wc * 64 + j * 16 + fr;
    float bvl = bv[col];
    #pragma unroll
    for (int i = 0; i < 4; ++i) {
      int rowb = m0 + wr * 64 + i * 16 + fq * 4;
      #pragma unroll
      for (int r = 0; r < 4; ++r) {
        if (rowb + r < QROWS)
          out[(size_t)(rowb + r) * 512 + col] = acc[i][j][r] + bvl;
      }
    }
  }
}

// ---------------- launch ----------------
extern "C" void kernel_launch(void* const* d_in, const int* in_sizes, int n_in,
                              void* d_out, int out_size, void* d_ws, size_t ws_size,
                              hipStream_t stream) {
  const float* x  = (const float*)d_in[0];
  const float* Wq = (const float*)d_in[1];
  const float* bq = (const float*)d_in[2];
  const float* Wk = (const float*)d_in[3];
  const float* Wv = (const float*)d_in[5];
  const float* bv = (const float*)d_in[6];
  float* out = (float*)d_out;

  char* ws = (char*)d_ws;
  ushort* wt   = (ushort*)ws;                        // 1.5 MiB: Wq^T|Wk^T|Wv^T
  ushort* kb   = (ushort*)(ws + 1572864);            // 16 MiB [16384][512]
  ushort* qc   = (ushort*)(ws + 1572864 + 16777216); // 4 MiB  [4040][512]
  ushort* ubuf = (ushort*)(ws + 1572864 + 16777216 + 4194304);  // 4 MiB

  hipLaunchKernelGGL(wprep_kernel, dim3(192), dim3(256), 0, stream, Wq, Wk, Wv, wt);
  hipLaunchKernelGGL(gemm_kernel, dim3(640), dim3(256), 0, stream,
                     x, wt, bq, kb, qc);
  hipLaunchKernelGGL(attn_kernel, dim3(512), dim3(256), 0, stream,
                     x, kb, qc, ubuf);
  hipLaunchKernelGGL(ogemm_kernel, dim3(128), dim3(256), 0, stream,
                     ubuf, wt + (size_t)1024 * 512, bv, out);
}